// Round 16
// baseline (176.474 us; speedup 1.0000x reference)
//
#include <hip/hip_runtime.h>
#include <hip/hip_bf16.h>

typedef unsigned short u16;
typedef unsigned int u32;
typedef __bf16 bf16x8 __attribute__((ext_vector_type(8)));
typedef u16 u16x8 __attribute__((ext_vector_type(8)));
typedef u16 u16x4 __attribute__((ext_vector_type(4)));
typedef float f32x4 __attribute__((ext_vector_type(4)));

#define T_SEQ 2048
#define DMODEL 2048
#define NHEAD 16
#define HDIM 128
#define ATT_SCALE 0.08838834764831843f

__device__ __forceinline__ u16 f2bf(float f) {
    return __builtin_bit_cast(u16, __float2bfloat16(f));
}
__device__ __forceinline__ bf16x8 as_bf(u16x8 v) {
    return __builtin_bit_cast(bf16x8, v);
}
__device__ __forceinline__ float lo2f(u32 w) { return __builtin_bit_cast(float, w << 16); }
__device__ __forceinline__ float hi2f(u32 w) { return __builtin_bit_cast(float, w & 0xffff0000u); }
__device__ __forceinline__ float bf2f(u16 v) { return __builtin_bit_cast(float, (u32)v << 16); }
__device__ __forceinline__ void gload_lds16(const u16* g, u16* l) {
    __builtin_amdgcn_global_load_lds(
        (const __attribute__((address_space(1))) u32*)(g),
        (__attribute__((address_space(3))) u32*)(l), 16, 0, 0);
}

// ------- fused prep: weight casts (blocks 0..8191) + RMSNorm (8192..10239) --
__global__ __launch_bounds__(256) void prep(const float* __restrict__ w1,
                                            const float* __restrict__ w2,
                                            const float* __restrict__ x,
                                            u16* __restrict__ d1,
                                            u16* __restrict__ d2,
                                            u16* __restrict__ xn) {
    const int b = blockIdx.x, tid = threadIdx.x;
    if (b < 8192) {
        int i = b * 256 + tid;
        const float* src; u16* dst; int k;
        if (i < 1572864) { src = w1; dst = d1; k = i; }
        else             { src = w2; dst = d2; k = i - 1572864; }
        float4 a = ((const float4*)src)[2 * k];
        float4 bb = ((const float4*)src)[2 * k + 1];
        u16x8 o;
        o[0] = f2bf(a.x); o[1] = f2bf(a.y); o[2] = f2bf(a.z); o[3] = f2bf(a.w);
        o[4] = f2bf(bb.x); o[5] = f2bf(bb.y); o[6] = f2bf(bb.z); o[7] = f2bf(bb.w);
        *(u16x8*)(dst + (size_t)k * 8) = o;
        return;
    }
    const int row = b - 8192;
    const float* xr = x + (size_t)row * DMODEL;
    float4 a = ((const float4*)xr)[2 * tid];
    float4 bb = ((const float4*)xr)[2 * tid + 1];
    float ss = a.x*a.x + a.y*a.y + a.z*a.z + a.w*a.w
             + bb.x*bb.x + bb.y*bb.y + bb.z*bb.z + bb.w*bb.w;
#pragma unroll
    for (int off = 32; off; off >>= 1) ss += __shfl_xor(ss, off);
    __shared__ float red[4];
    if ((tid & 63) == 0) red[tid >> 6] = ss;
    __syncthreads();
    float tot = red[0] + red[1] + red[2] + red[3];
    float r = rsqrtf(tot * (1.f / DMODEL) + 1e-6f);
    u16x8 o;
    o[0] = f2bf(a.x*r); o[1] = f2bf(a.y*r); o[2] = f2bf(a.z*r); o[3] = f2bf(a.w*r);
    o[4] = f2bf(bb.x*r); o[5] = f2bf(bb.y*r); o[6] = f2bf(bb.z*r); o[7] = f2bf(bb.w*r);
    *(u16x8*)(xn + (size_t)row * DMODEL + tid * 8) = o;
}

// ================= shared 8-phase GEMM machinery ===========================
#define VM2 asm volatile("s_waitcnt vmcnt(2)" ::: "memory");
#define VM4 asm volatile("s_waitcnt vmcnt(4)" ::: "memory");
#define VM0 asm volatile("s_waitcnt vmcnt(0)" ::: "memory");

#define ENDP                                                                  \
  __builtin_amdgcn_s_barrier();                                               \
  __builtin_amdgcn_sched_barrier(0);

// ---- 256x192 qkv GEMM, 6-phase uniform-16-MFMA schedule (r13) ----
#define LDA6(DST, BUF, MH)                                                    \
  _Pragma("unroll") for (int mq = 0; mq < 4; ++mq) {                          \
    int ra = wr + (MH) * 64 + mq * 16 + fr;                                   \
    int sw = ra & 7;                                                          \
    _Pragma("unroll") for (int k2 = 0; k2 < 2; ++k2)                          \
      DST[mq][k2] = *(const u16x8*)(sA[BUF] + ra * 64 +                       \
                                    ((((k2 << 2) | fg) ^ sw) << 3));          \
  }

#define LDB0_192(BUF)                                                         \
  _Pragma("unroll") for (int nq = 0; nq < 2; ++nq) {                          \
    int rb = wc + nq * 16 + fr;                                               \
    int sw = rb & 7;                                                          \
    _Pragma("unroll") for (int k2 = 0; k2 < 2; ++k2)                          \
      bv[nq][k2] = *(const u16x8*)(sB[BUF] + rb * 64 +                        \
                                   ((((k2 << 2) | fg) ^ sw) << 3));           \
  }

#define LDB1_192(BUF)                                                         \
  {                                                                           \
    int rb = wc + 32 + fr;                                                    \
    int sw = rb & 7;                                                          \
    _Pragma("unroll") for (int k2 = 0; k2 < 2; ++k2)                          \
      bv1[k2] = *(const u16x8*)(sB[BUF] + rb * 64 +                           \
                                ((((k2 << 2) | fg) ^ sw) << 3));              \
  }

#define MN0(AV, MH)                                                           \
  __builtin_amdgcn_s_barrier();                                               \
  __builtin_amdgcn_s_setprio(1);                                              \
  _Pragma("unroll") for (int k2 = 0; k2 < 2; ++k2)                            \
    _Pragma("unroll") for (int mq = 0; mq < 4; ++mq)                          \
      _Pragma("unroll") for (int nq = 0; nq < 2; ++nq)                        \
        acc[(MH) * 4 + mq][nq] = __builtin_amdgcn_mfma_f32_16x16x32_bf16(     \
            as_bf(AV[mq][k2]), as_bf(bv[nq][k2]), acc[(MH) * 4 + mq][nq],     \
            0, 0, 0);                                                         \
  __builtin_amdgcn_s_setprio(0);

#define MN1B                                                                  \
  __builtin_amdgcn_s_barrier();                                               \
  __builtin_amdgcn_s_setprio(1);                                              \
  _Pragma("unroll") for (int k2 = 0; k2 < 2; ++k2)                            \
    _Pragma("unroll") for (int mq = 0; mq < 4; ++mq) {                        \
      acc[mq][2] = __builtin_amdgcn_mfma_f32_16x16x32_bf16(                   \
          as_bf(av[mq][k2]), as_bf(bv1[k2]), acc[mq][2], 0, 0, 0);            \
      acc[4 + mq][2] = __builtin_amdgcn_mfma_f32_16x16x32_bf16(               \
          as_bf(av2[mq][k2]), as_bf(bv1[k2]), acc[4 + mq][2], 0, 0, 0);       \
    }                                                                         \
  __builtin_amdgcn_s_setprio(0);

__global__ __launch_bounds__(512) void gemm192(const u16* __restrict__ A,
                                               const u16* __restrict__ B,
                                               u16* __restrict__ C,
                                               int M, int N, int K) {
    extern __shared__ char smem[];
    const int tid = threadIdx.x, lane = tid & 63, wid = tid >> 6;
    const int bm = blockIdx.y * 256, bn = blockIdx.x * 192;
    const int wr = (wid >> 2) * 128, wc = (wid & 3) * 48;
    const int fr = lane & 15, fg = lane >> 4;

    u16* sA[2] = {(u16*)smem, (u16*)(smem + 57344)};
    u16* sB[2] = {(u16*)(smem + 32768), (u16*)(smem + 90112)};

    const int cs = (((tid & 7) ^ ((tid >> 3) & 7)) << 3);
    const int s8 = (tid & 7) << 3;
    const int rr6 = tid >> 3;

    auto stA = [&](int buf, int k0, int mh) {
#pragma unroll
        for (int j = 0; j < 2; ++j) {
            int r = j * 128 + mh * 64 + rr6;
            gload_lds16(A + (size_t)(bm + r) * K + k0 + cs, sA[buf] + r * 64 + s8);
        }
    };
    auto stB = [&](int buf, int k0, int bt) {
        int r = bt * 64 + rr6;
        gload_lds16(B + (size_t)(bn + r) * K + k0 + cs, sB[buf] + r * 64 + s8);
    };

    f32x4 acc[8][3] = {};
    u16x8 av[4][2], av2[4][2], bv[2][2], bv1[2];
    const int nt = K >> 6;

    stA(0, 0, 0); stA(0, 0, 1); stB(0, 0, 0); stB(0, 0, 1); stB(0, 0, 2);
    stA(1, 64, 0); stA(1, 64, 1);
    VM4
    __builtin_amdgcn_s_barrier();
    __builtin_amdgcn_sched_barrier(0);

    for (int it = 0; it < (nt >> 1); ++it) {
        const int kc = it << 7;
        const int kn1 = kc + 64, kn2 = kc + 128, kn3 = kc + 192;
        const bool st2 = (kn2 < K), st3 = (kn3 < K);

        LDA6(av, 0, 0) LDB0_192(0)
        stB(1, kn1, 0); stB(1, kn1, 1);
        MN0(av, 0) ENDP
        LDB1_192(0) LDA6(av2, 0, 1)
        stB(1, kn1, 2);
        if (st2) stA(0, kn2, 0);
        MN1B ENDP
        if (st2) stA(0, kn2, 1);
        MN0(av2, 1)
        if (st2) { VM4 } else { VM0 }
        ENDP
        LDA6(av, 1, 0) LDB0_192(1)
        if (st2) { stB(0, kn2, 0); stB(0, kn2, 1); }
        MN0(av, 0) ENDP
        LDB1_192(1) LDA6(av2, 1, 1)
        if (st2) stB(0, kn2, 2);
        if (st3) stA(1, kn3, 0);
        MN1B ENDP
        if (st3) stA(1, kn3, 1);
        MN0(av2, 1)
        if (st3) { VM4 } else { VM0 }
        ENDP
    }

#pragma unroll
    for (int am = 0; am < 8; ++am)
#pragma unroll
        for (int bq = 0; bq < 3; ++bq)
#pragma unroll
            for (int r = 0; r < 4; ++r) {
                int row = bm + wr + am * 16 + fg * 4 + r;
                int col = bn + wc + bq * 16 + fr;
                C[(size_t)row * N + col] = f2bf(acc[am][bq][r]);
            }
}

// ---- 128x128 8-phase variant for out-proj (resid epilogue) ----
#define LDAH(BUF, MH)                                                         \
  _Pragma("unroll") for (int mq = 0; mq < 2; ++mq) {                          \
    int ra = wr + (MH) * 32 + mq * 16 + fr;                                   \
    int sw = ra & 7;                                                          \
    _Pragma("unroll") for (int k2 = 0; k2 < 2; ++k2)                          \
      avh[mq][k2] = *(const u16x8*)(sA[BUF] + ra * 64 +                       \
                                    ((((k2 << 2) | fg) ^ sw) << 3));          \
  }

#define LDBH(BUF, NH)                                                         \
  _Pragma("unroll") for (int nq = 0; nq < 2; ++nq) {                          \
    int rb = wc + (NH) * 32 + nq * 16 + fr;                                   \
    int sw = rb & 7;                                                          \
    _Pragma("unroll") for (int k2 = 0; k2 < 2; ++k2)                          \
      bvh[nq][k2] = *(const u16x8*)(sB[BUF] + rb * 64 +                       \
                                    ((((k2 << 2) | fg) ^ sw) << 3));          \
  }

#define MFMAQH(MH, NH)                                                        \
  __builtin_amdgcn_s_barrier();                                               \
  __builtin_amdgcn_s_setprio(1);                                              \
  _Pragma("unroll") for (int k2 = 0; k2 < 2; ++k2)                            \
    _Pragma("unroll") for (int mq = 0; mq < 2; ++mq)                          \
      _Pragma("unroll") for (int nq = 0; nq < 2; ++nq)                        \
        acc[(MH) * 2 + mq][(NH) * 2 + nq] =                                   \
            __builtin_amdgcn_mfma_f32_16x16x32_bf16(                          \
                as_bf(avh[mq][k2]), as_bf(bvh[nq][k2]),                       \
                acc[(MH) * 2 + mq][(NH) * 2 + nq], 0, 0, 0);                  \
  __builtin_amdgcn_s_setprio(0);

__global__ __launch_bounds__(256) void gemm128(const u16* __restrict__ A,
                                               const u16* __restrict__ B,
                                               float* __restrict__ C,
                                               const float* __restrict__ resid,
                                               int M, int N, int K) {
    extern __shared__ char smem[];
    const int tid = threadIdx.x, lane = tid & 63, wid = tid >> 6;
    const int bm = blockIdx.y * 128, bn = blockIdx.x * 128;
    const int wr = (wid >> 1) * 64, wc = (wid & 1) * 64;
    const int fr = lane & 15, fg = lane >> 4;

    u16* sA[2] = {(u16*)smem, (u16*)(smem + 32768)};
    u16* sB[2] = {(u16*)(smem + 16384), (u16*)(smem + 49152)};

    const int cs = (((tid & 7) ^ ((tid >> 3) & 7)) << 3);
    const int s8 = (tid & 7) << 3;
    const int rr5 = tid >> 3;

    auto stA = [&](int buf, int k0, int mh) {
#pragma unroll
        for (int j = 0; j < 2; ++j) {
            int r = j * 64 + mh * 32 + rr5;
            gload_lds16(A + (size_t)(bm + r) * K + k0 + cs, sA[buf] + r * 64 + s8);
        }
    };
    auto stB = [&](int buf, int k0, int nh) {
#pragma unroll
        for (int j = 0; j < 2; ++j) {
            int r = j * 64 + nh * 32 + rr5;
            gload_lds16(B + (size_t)(bn + r) * K + k0 + cs, sB[buf] + r * 64 + s8);
        }
    };

    f32x4 acc[4][4] = {};
    u16x8 avh[2][2], bvh[2][2];
    const int nt = K >> 6;

    stA(0, 0, 0); stA(0, 0, 1); stB(0, 0, 0); stB(0, 0, 1);
    stA(1, 64, 0); stB(1, 64, 1);
    VM4
    __builtin_amdgcn_s_barrier();
    __builtin_amdgcn_sched_barrier(0);

    for (int it = 0; it < (nt >> 1); ++it) {
        const int kc = it << 7;
        const int kn1 = kc + 64, kn2 = kc + 128, kn3 = kc + 192;
        const bool st2 = (kn2 < K), st3 = (kn3 < K);

        LDAH(0, 0) LDBH(0, 0)
        stA(1, kn1, 1);
        MFMAQH(0, 0) ENDP
        LDBH(0, 1)
        stB(1, kn1, 0);
        MFMAQH(0, 1) ENDP
        LDAH(0, 1)
        if (st2) stA(0, kn2, 0);
        MFMAQH(1, 1) ENDP
        LDBH(0, 0)
        if (st2) stB(0, kn2, 1);
        MFMAQH(1, 0)
        if (st2) { VM4 } else { VM0 }
        ENDP
        LDAH(1, 0) LDBH(1, 0)
        if (st2) stA(0, kn2, 1);
        MFMAQH(0, 0) ENDP
        LDBH(1, 1)
        if (st2) stB(0, kn2, 0);
        MFMAQH(0, 1) ENDP
        LDAH(1, 1)
        if (st3) stA(1, kn3, 0);
        MFMAQH(1, 1) ENDP
        LDBH(1, 0)
        if (st3) stB(1, kn3, 1);
        MFMAQH(1, 0)
        VM4
        ENDP
    }

#pragma unroll
    for (int am = 0; am < 4; ++am)
#pragma unroll
        for (int bq = 0; bq < 4; ++bq)
#pragma unroll
            for (int r = 0; r < 4; ++r) {
                int row = bm + wr + am * 16 + fg * 4 + r;
                int col = bn + wc + bq * 16 + fr;
                float val = acc[am][bq][r] + resid[(size_t)row * N + col];
                C[(size_t)row * N + col] = val;
            }
}

// ---------------- per-head RMSNorm + RoPE (vectorized, bf16 qkv) -----------
__global__ __launch_bounds__(256) void rope_split(const u16* __restrict__ qkv,
                                                  const float* __restrict__ cosb,
                                                  const float* __restrict__ sinb,
                                                  u16* __restrict__ q_bf,
                                                  u16* __restrict__ k_bf,
                                                  float* __restrict__ k_out,
                                                  float* __restrict__ v_out) {
    const int t = blockIdx.x, tid = threadIdx.x, wid = tid >> 6, lane = tid & 63;
    const u16* row = qkv + (size_t)t * (3 * DMODEL);
    const int dp = (lane & 31) << 1;
    float2 c2 = *(const float2*)(cosb + t * 64 + dp);
    float2 s2 = *(const float2*)(sinb + t * 64 + dp);
    const bool hi = lane >= 32;

    for (int task = wid; task < 32; task += 4) {
        u32 w = *(const u32*)(row + task * 128 + lane * 2);
        float xa = lo2f(w), xb = hi2f(w);
        float ss = xa * xa + xb * xb;
#pragma unroll
        for (int off = 32; off; off >>= 1) ss += __shfl_xor(ss, off);
        float rn = rsqrtf(ss * (1.f / 128.f) + 1e-6f);
        float pa = __shfl_xor(xa, 32), pb = __shfl_xor(xb, 32);
        float oa, ob;
        if (!hi) {
            oa = (xa * c2.x - pa * s2.x) * rn;
            ob = (xb * c2.y - pb * s2.y) * rn;
        } else {
            oa = (pa * s2.x + xa * c2.x) * rn;
            ob = (pb * s2.y + xb * c2.y) * rn;
        }
        u32 pk = (u32)f2bf(oa) | ((u32)f2bf(ob) << 16);
        if (task < 16) {
            *(u32*)(q_bf + ((size_t)task * T_SEQ + t) * 128 + lane * 2) = pk;
        } else {
            int hh = task - 16;
            *(u32*)(k_bf + ((size_t)hh * T_SEQ + t) * 128 + lane * 2) = pk;
            float2 kk; kk.x = oa; kk.y = ob;
            *(float2*)(k_out + (size_t)t * DMODEL + hh * 128 + lane * 2) = kk;
        }
    }
    {
        u16x8 vv = *(const u16x8*)(row + 2 * DMODEL + tid * 8);
        float4 f0, f1;
        f0.x = bf2f(vv[0]); f0.y = bf2f(vv[1]); f0.z = bf2f(vv[2]); f0.w = bf2f(vv[3]);
        f1.x = bf2f(vv[4]); f1.y = bf2f(vv[5]); f1.z = bf2f(vv[6]); f1.w = bf2f(vv[7]);
        *(float4*)(v_out + (size_t)t * DMODEL + tid * 8) = f0;
        *(float4*)(v_out + (size_t)t * DMODEL + tid * 8 + 4) = f1;
    }
}

// ---------------- V transpose: qkv bf16 -> vt bf16 [h][128][T] -------------
__global__ __launch_bounds__(256) void vtrans(const u16* __restrict__ qkv,
                                              u16* __restrict__ vt) {
    const int b = blockIdx.x, tid = threadIdx.x;
    const int head = b >> 7;
    const int i = (b & 127) * 256 + tid;
    const int d = i & 127, tc = i >> 7;
    u16x8 o;
#pragma unroll
    for (int j = 0; j < 8; ++j)
        o[j] = qkv[(size_t)(tc * 8 + j) * (3 * DMODEL) + 2 * DMODEL + head * 128 + d];
    *(u16x8*)&vt[((size_t)head * 128 + d) * T_SEQ + tc * 8] = o;
}

// ---------------- causal flash attention, kv-split + split prefetch --------
// Single-buffer; K_{i+1} issued right after QK_i's barrier (hides under
// softmax+PV), V_{i+1} issued right after PV_i's barrier (hides under
// QK_{i+1}). Ledger: before PV_i, outstanding = V_i(old4)+K_{i+1}(4) ->
// vmcnt(4); after issuing V_{i+1}, outstanding = K_{i+1}(old4)+V_{i+1}(4)
// -> vmcnt(4) drains K_{i+1} before next QK. Tails degrade to vmcnt(0).
__global__ __launch_bounds__(256) void attn_part(const u16* __restrict__ qb,
                                                 const u16* __restrict__ kb,
                                                 const u16* __restrict__ vtb,
                                                 u16* __restrict__ opart,
                                                 float* __restrict__ ml) {
    __shared__ u16 Ks[64 * 128];
    __shared__ u16 Vs[128 * 64];
    __shared__ u16 Ps[4][16 * 64];

    const int bid = blockIdx.x;
    const int r8 = bid & 7, s = bid >> 3;
    const int hs = s >> 6, g = (s >> 5) & 1, m = s & 31;
    const int head = r8 + (hs << 3);
    const int qt = g ? (31 - m) : m;
    const int nt = qt + 1;
    const int h0c = (nt + 1) >> 1;
    const int first = g ? h0c : 0;
    const int count = g ? (nt - h0c) : h0c;
    const int pidx = (head * 32 + qt) * 2 + g;

    const int tid = threadIdx.x, wid = tid >> 6, lane = tid & 63;
    const int fr = lane & 15, fg = lane >> 4;
    const u16* kh = kb + (size_t)head * T_SEQ * 128;
    const u16* vth = vtb + (size_t)head * 128 * T_SEQ;
    const u16* qh = qb + (size_t)head * T_SEQ * 128;
    const int q0 = qt * 64 + wid * 16;
    const int qrow_g = q0 + fr;

    u16x8 bq[4];
    {
        const u16* qrow = qh + (size_t)(q0 + fr) * 128 + fg * 8;
#pragma unroll
        for (int cc = 0; cc < 4; ++cc) bq[cc] = *(const u16x8*)(qrow + cc * 32);
    }

    auto stageK = [&](int kv0) {
#pragma unroll
        for (int i = 0; i < 4; ++i) {
            int idx = i * 256 + tid;
            int r = idx >> 4;
            int cbs = ((idx & 15) << 4) ^ ((r & 7) << 4);
            gload_lds16(kh + (size_t)(kv0 + r) * 128 + (cbs >> 1), &Ks[idx * 8]);
        }
    };
    auto stageV = [&](int kv0) {
#pragma unroll
        for (int i = 0; i < 4; ++i) {
            int idx = i * 256 + tid;
            int d = idx >> 3;
            int cbs = ((idx & 7) << 4) ^ ((d & 7) << 4);
            gload_lds16(vth + (size_t)d * T_SEQ + kv0 + (cbs >> 1), &Vs[idx * 8]);
        }
    };

    f32x4 o[8] = {};
    float m_run = -1e30f, l_run = 0.f;

    if (count > 0) {
        stageK(first * 64);
        stageV(first * 64);
        asm volatile("s_waitcnt vmcnt(0)" ::: "memory");
    }
    __builtin_amdgcn_s_barrier();
    __builtin_amdgcn_sched_barrier(0);

    for (int i = 0; i < count; ++i) {
        const int kv0 = (first + i) * 64;
        const bool more = (i + 1) < count;

        const char* ksb = (const char*)&Ks[0];
        const char* vsb = (const char*)&Vs[0];
        char* psb = (char*)&Ps[wid][0];

        // ---- QK^T (reads Ks) ----
        float p[4][4];
        float mx = -1e30f;
        const bool diag = (kv0 + 64 > q0);
#pragma unroll
        for (int st = 0; st < 4; ++st) {
            f32x4 sacc = {0.f, 0.f, 0.f, 0.f};
#pragma unroll
            for (int c4 = 0; c4 < 4; ++c4) {
                int r = st * 16 + fr;
                int cb = c4 * 64 + fg * 16;
                u16x8 ak = *(const u16x8*)(ksb + r * 256 + (cb ^ ((r & 7) << 4)));
                sacc = __builtin_amdgcn_mfma_f32_16x16x32_bf16(
                    as_bf(ak), as_bf(bq[c4]), sacc, 0, 0, 0);
            }
#pragma unroll
            for (int rr = 0; rr < 4; ++rr) {
                float sv = sacc[rr] * ATT_SCALE;
                if (diag) {
                    int kvg = kv0 + st * 16 + fg * 4 + rr;
                    sv = (kvg <= qrow_g) ? sv : -1e30f;
                }
                p[st][rr] = sv;
                mx = fmaxf(mx, sv);
            }
        }
        __builtin_amdgcn_s_barrier();        // all waves done reading Ks
        if (more) stageK(kv0 + 64);          // K_{i+1} in flight under SM+PV
        __builtin_amdgcn_sched_barrier(0);

        // ---- softmax ----
        mx = fmaxf(mx, __shfl_xor(mx, 16));
        mx = fmaxf(mx, __shfl_xor(mx, 32));

        if (__all(mx - m_run <= 8.f)) {
            float rs = 0.f;
#pragma unroll
            for (int st = 0; st < 4; ++st) {
                u16x4 pw;
#pragma unroll
                for (int rr = 0; rr < 4; ++rr) {
                    float e = __expf(p[st][rr] - m_run);
                    rs += e;
                    pw[rr] = f2bf(e);
                }
                *(u16x4*)(psb + fr * 128 + ((st * 32 + fg * 8) ^ ((fr & 7) << 4))) = pw;
            }
            rs += __shfl_xor(rs, 16);
            rs += __shfl_xor(rs, 32);
            l_run += rs;
        } else {
            float m_new = fmaxf(m_run, mx);
            float corr = __expf(m_run - m_new);
            float rs = 0.f;
#pragma unroll
            for (int st = 0; st < 4; ++st) {
                u16x4 pw;
#pragma unroll
                for (int rr = 0; rr < 4; ++rr) {
                    float e = __expf(p[st][rr] - m_new);
                    rs += e;
                    pw[rr] = f2bf(e);
                }
                *(u16x4*)(psb + fr * 128 + ((st * 32 + fg * 8) ^ ((fr & 7) << 4))) = pw;
            }
            rs += __shfl_xor(rs, 16);
            rs += __shfl_xor(rs, 32);
            l_run = l_run * corr + rs;
            m_run = m_new;
            float ct[4];
#pragma unroll
            for (int rr = 0; rr < 4; ++rr) ct[rr] = __shfl(corr, fg * 4 + rr);
#pragma unroll
            for (int f = 0; f < 8; ++f)
#pragma unroll
                for (int rr = 0; rr < 4; ++rr) o[f][rr] *= ct[rr];
        }

        // V_i already landed (drained last iter / prologue); K_{i+1} may be
        // in flight (4 youngest) -> vmcnt(4) only orders V_i (already done);
        // barrier syncs the P writes' visibility is per-wave (not needed) and
        // keeps waves phase-aligned before PV.
        if (more) { asm volatile("s_waitcnt vmcnt(4)" ::: "memory"); }
        else      { asm volatile("s_waitcnt vmcnt(0)" ::: "memory"); }
        __builtin_amdgcn_s_barrier();
        __builtin_amdgcn_sched_barrier(0);

        // ---- PV (reads Vs) ----
#pragma unroll
        for (int ks = 0; ks < 2; ++ks) {
            u16x8 pa = *(const u16x8*)(psb + fr * 128 + ((ks * 64 + fg * 16) ^ ((fr & 7) << 4)));
#pragma unroll
            for (int f = 0; f < 8; ++f) {
                int d = f * 16 + fr;
                u16x8 vB = *(const u16x8*)(vsb + d * 128 + ((ks * 64 + fg * 16) ^ ((d & 7) << 4)));
                o[f] = __builtin_amdgcn_mfma_f32_16x16x32_bf16(
                    as_bf(pa), as_bf(vB), o[f], 0, 0, 0);
            }
        }
        __builtin_amdgcn_s_barrier();        // all waves done reading Vs
        __builtin_amdgcn_sched_barrier(0);
        if (more) {
            stageV(kv0 + 64);                // V_{i+1} in flight under next QK
            asm volatile("s_waitcnt vmcnt(4)" ::: "memory");  // K_{i+1} landed
        }
        __builtin_amdgcn_s_barrier();        // Ks ready for next QK
        __builtin_amdgcn_sched_barrier(0);
    }

    u16* op = opart + (size_t)pidx * 8192;
#pragma unroll
    for (int f = 0; f < 8; ++f)
#pragma unroll
        for (int rr = 0; rr < 4; ++rr)
            op[(wid * 16 + fg * 4 + rr) * 128 + f * 16 + fr] = f2bf(o[f][rr]);
    if (fg == 0) {
        ml[pidx * 128 + wid * 16 + fr] = m_run;
        ml[pidx * 128 + 64 + wid * 16 + fr] = l_run;
    }
}

// ---------------- merge kv-split partials -> x_bf --------------------------
__global__ __launch_bounds__(256) void attn_merge(const u16* __restrict__ opart,
                                                  const float* __restrict__ ml,
                                                  u16* __restrict__ xout) {
    const int b = blockIdx.x, tid = threadIdx.x;
    const int head = b >> 5, qt = b & 31;
    const int p0 = b * 2, p1 = b * 2 + 1;
    const int row = tid >> 2, d0 = (tid & 3) * 32;

    float m0 = ml[p0 * 128 + row], l0 = ml[p0 * 128 + 64 + row];
    float m1 = ml[p1 * 128 + row], l1 = ml[p1 * 128 + 64 + row];
    float M = fmaxf(m0, m1);
    float w0 = __expf(m0 - M), w1 = __expf(m1 - M);
    float inv = 1.f / (l0 * w0 + l1 * w1);
    w0 *= inv; w1 *= inv;

    const u16* a0 = opart + (size_t)p0 * 8192 + row * 128 + d0;
    const u16* a1 = opart + (size_t)p1 * 8192 + row * 128 + d0;
    u16* dst = xout + (size_t)(qt * 64 + row) * DMODEL + head * 128 + d0;
#pragma unroll
    for (int j = 0; j < 4; ++j) {
        u16x8 v0 = *(const u16x8*)(a0 + j * 8);
        u16x8 v1 = *(const u16x8*)(a1 + j * 8);
        u16x8 ov;
#pragma unroll
        for (int e = 0; e < 8; ++e)
            ov[e] = f2bf(bf2f(v0[e]) * w0 + bf2f(v1[e]) * w1);
        *(u16x8*)(dst + j * 8) = ov;
    }
}

extern "C" void kernel_launch(void* const* d_in, const int* in_sizes, int n_in,
                              void* d_out, int out_size, void* d_ws, size_t ws_size,
                              hipStream_t stream) {
    const float* x_in = (const float*)d_in[0];
    const float* w_qkv = (const float*)d_in[1];
    const float* w_o = (const float*)d_in[2];
    const float* cosb = (const float*)d_in[3];
    const float* sinb = (const float*)d_in[4];

    float* out = (float*)d_out;
    float* k_out = out + 4194304;
    float* v_out = out + 8388608;

    char* ws = (char*)d_ws;
    u16* xn    = (u16*)(ws);                         // 8 MiB  [T][D] bf16
    u16* w_bf  = (u16*)(ws + (size_t)(8u << 20));    // 24 MiB [3D][D] bf16
    u16* o_bf  = (u16*)(ws + (size_t)(32u << 20));   // 8 MiB  [D][D] bf16
    u16* qkv   = (u16*)(ws + (size_t)(40u << 20));   // 24 MiB [T][3D] bf16
    u16* q_bf  = (u16*)(ws + (size_t)(64u << 20));   // 8 MiB  [h][T][hd]
    u16* k_bf  = (u16*)(ws + (size_t)(72u << 20));   // 8 MiB
    u16* vt_bf = (u16*)(ws + (size_t)(80u << 20));   // 8 MiB  [h][hd][T]
    u16* x_bf  = (u16*)(ws + (size_t)(88u << 20));   // 8 MiB  [T][D]
    u16* opart = (u16*)(ws + (size_t)(40u << 20));   // 16 MiB (aliases dead qkv)
    float* mlb = (float*)(ws + (size_t)(56u << 20)); // 512 KiB

    (void)hipFuncSetAttribute(reinterpret_cast<const void*>(&gemm192),
                              hipFuncAttributeMaxDynamicSharedMemorySize, 114688);
    (void)hipFuncSetAttribute(reinterpret_cast<const void*>(&gemm128),
                              hipFuncAttributeMaxDynamicSharedMemorySize, 65536);

    prep<<<10240, 256, 0, stream>>>(w_qkv, w_o, x_in, w_bf, o_bf, xn);
    gemm192<<<dim3(32, 8), 512, 114688, stream>>>(xn, w_bf, qkv, 2048, 6144, 2048);
    rope_split<<<2048, 256, 0, stream>>>(qkv, cosb, sinb, q_bf, k_bf, k_out, v_out);
    vtrans<<<2048, 256, 0, stream>>>(qkv, vt_bf);
    attn_part<<<1024, 256, 0, stream>>>(q_bf, k_bf, vt_bf, opart, mlb);
    attn_merge<<<512, 256, 0, stream>>>(opart, mlb, x_bf);
    gemm128<<<dim3(16, 16), 256, 65536, stream>>>(x_bf, o_bf, out, x_in, 2048, 2048, 2048);
}

// Round 17
// 175.511 us; speedup vs baseline: 1.0055x; 1.0055x over previous
//
#include <hip/hip_runtime.h>
#include <hip/hip_bf16.h>

typedef unsigned short u16;
typedef unsigned int u32;
typedef __bf16 bf16x8 __attribute__((ext_vector_type(8)));
typedef u16 u16x8 __attribute__((ext_vector_type(8)));
typedef u16 u16x4 __attribute__((ext_vector_type(4)));
typedef float f32x4 __attribute__((ext_vector_type(4)));

#define T_SEQ 2048
#define DMODEL 2048
#define NHEAD 16
#define HDIM 128
#define ATT_SCALE 0.08838834764831843f

__device__ __forceinline__ u16 f2bf(float f) {
    return __builtin_bit_cast(u16, __float2bfloat16(f));
}
__device__ __forceinline__ bf16x8 as_bf(u16x8 v) {
    return __builtin_bit_cast(bf16x8, v);
}
__device__ __forceinline__ float lo2f(u32 w) { return __builtin_bit_cast(float, w << 16); }
__device__ __forceinline__ float hi2f(u32 w) { return __builtin_bit_cast(float, w & 0xffff0000u); }
__device__ __forceinline__ float bf2f(u16 v) { return __builtin_bit_cast(float, (u32)v << 16); }
__device__ __forceinline__ void gload_lds16(const u16* g, u16* l) {
    __builtin_amdgcn_global_load_lds(
        (const __attribute__((address_space(1))) u32*)(g),
        (__attribute__((address_space(3))) u32*)(l), 16, 0, 0);
}

// ------- fused prep: weight casts (blocks 0..8191) + RMSNorm (8192..10239) --
__global__ __launch_bounds__(256) void prep(const float* __restrict__ w1,
                                            const float* __restrict__ w2,
                                            const float* __restrict__ x,
                                            u16* __restrict__ d1,
                                            u16* __restrict__ d2,
                                            u16* __restrict__ xn) {
    const int b = blockIdx.x, tid = threadIdx.x;
    if (b < 8192) {
        int i = b * 256 + tid;
        const float* src; u16* dst; int k;
        if (i < 1572864) { src = w1; dst = d1; k = i; }
        else             { src = w2; dst = d2; k = i - 1572864; }
        float4 a = ((const float4*)src)[2 * k];
        float4 bb = ((const float4*)src)[2 * k + 1];
        u16x8 o;
        o[0] = f2bf(a.x); o[1] = f2bf(a.y); o[2] = f2bf(a.z); o[3] = f2bf(a.w);
        o[4] = f2bf(bb.x); o[5] = f2bf(bb.y); o[6] = f2bf(bb.z); o[7] = f2bf(bb.w);
        *(u16x8*)(dst + (size_t)k * 8) = o;
        return;
    }
    const int row = b - 8192;
    const float* xr = x + (size_t)row * DMODEL;
    float4 a = ((const float4*)xr)[2 * tid];
    float4 bb = ((const float4*)xr)[2 * tid + 1];
    float ss = a.x*a.x + a.y*a.y + a.z*a.z + a.w*a.w
             + bb.x*bb.x + bb.y*bb.y + bb.z*bb.z + bb.w*bb.w;
#pragma unroll
    for (int off = 32; off; off >>= 1) ss += __shfl_xor(ss, off);
    __shared__ float red[4];
    if ((tid & 63) == 0) red[tid >> 6] = ss;
    __syncthreads();
    float tot = red[0] + red[1] + red[2] + red[3];
    float r = rsqrtf(tot * (1.f / DMODEL) + 1e-6f);
    u16x8 o;
    o[0] = f2bf(a.x*r); o[1] = f2bf(a.y*r); o[2] = f2bf(a.z*r); o[3] = f2bf(a.w*r);
    o[4] = f2bf(bb.x*r); o[5] = f2bf(bb.y*r); o[6] = f2bf(bb.z*r); o[7] = f2bf(bb.w*r);
    *(u16x8*)(xn + (size_t)row * DMODEL + tid * 8) = o;
}

// ================= shared 8-phase GEMM machinery ===========================
#define VM2 asm volatile("s_waitcnt vmcnt(2)" ::: "memory");
#define VM4 asm volatile("s_waitcnt vmcnt(4)" ::: "memory");
#define VM0 asm volatile("s_waitcnt vmcnt(0)" ::: "memory");

#define ENDP                                                                  \
  __builtin_amdgcn_s_barrier();                                               \
  __builtin_amdgcn_sched_barrier(0);

// ---- 256x192 qkv GEMM, 6-phase uniform-16-MFMA schedule (r13) ----
#define LDA6(DST, BUF, MH)                                                    \
  _Pragma("unroll") for (int mq = 0; mq < 4; ++mq) {                          \
    int ra = wr + (MH) * 64 + mq * 16 + fr;                                   \
    int sw = ra & 7;                                                          \
    _Pragma("unroll") for (int k2 = 0; k2 < 2; ++k2)                          \
      DST[mq][k2] = *(const u16x8*)(sA[BUF] + ra * 64 +                       \
                                    ((((k2 << 2) | fg) ^ sw) << 3));          \
  }

#define LDB0_192(BUF)                                                         \
  _Pragma("unroll") for (int nq = 0; nq < 2; ++nq) {                          \
    int rb = wc + nq * 16 + fr;                                               \
    int sw = rb & 7;                                                          \
    _Pragma("unroll") for (int k2 = 0; k2 < 2; ++k2)                          \
      bv[nq][k2] = *(const u16x8*)(sB[BUF] + rb * 64 +                        \
                                   ((((k2 << 2) | fg) ^ sw) << 3));           \
  }

#define LDB1_192(BUF)                                                         \
  {                                                                           \
    int rb = wc + 32 + fr;                                                    \
    int sw = rb & 7;                                                          \
    _Pragma("unroll") for (int k2 = 0; k2 < 2; ++k2)                          \
      bv1[k2] = *(const u16x8*)(sB[BUF] + rb * 64 +                           \
                                ((((k2 << 2) | fg) ^ sw) << 3));              \
  }

#define MN0(AV, MH)                                                           \
  __builtin_amdgcn_s_barrier();                                               \
  __builtin_amdgcn_s_setprio(1);                                              \
  _Pragma("unroll") for (int k2 = 0; k2 < 2; ++k2)                            \
    _Pragma("unroll") for (int mq = 0; mq < 4; ++mq)                          \
      _Pragma("unroll") for (int nq = 0; nq < 2; ++nq)                        \
        acc[(MH) * 4 + mq][nq] = __builtin_amdgcn_mfma_f32_16x16x32_bf16(     \
            as_bf(AV[mq][k2]), as_bf(bv[nq][k2]), acc[(MH) * 4 + mq][nq],     \
            0, 0, 0);                                                         \
  __builtin_amdgcn_s_setprio(0);

#define MN1B                                                                  \
  __builtin_amdgcn_s_barrier();                                               \
  __builtin_amdgcn_s_setprio(1);                                              \
  _Pragma("unroll") for (int k2 = 0; k2 < 2; ++k2)                            \
    _Pragma("unroll") for (int mq = 0; mq < 4; ++mq) {                        \
      acc[mq][2] = __builtin_amdgcn_mfma_f32_16x16x32_bf16(                   \
          as_bf(av[mq][k2]), as_bf(bv1[k2]), acc[mq][2], 0, 0, 0);            \
      acc[4 + mq][2] = __builtin_amdgcn_mfma_f32_16x16x32_bf16(               \
          as_bf(av2[mq][k2]), as_bf(bv1[k2]), acc[4 + mq][2], 0, 0, 0);       \
    }                                                                         \
  __builtin_amdgcn_s_setprio(0);

__global__ __launch_bounds__(512) void gemm192(const u16* __restrict__ A,
                                               const u16* __restrict__ B,
                                               u16* __restrict__ C,
                                               int M, int N, int K) {
    extern __shared__ char smem[];
    const int tid = threadIdx.x, lane = tid & 63, wid = tid >> 6;
    const int bm = blockIdx.y * 256, bn = blockIdx.x * 192;
    const int wr = (wid >> 2) * 128, wc = (wid & 3) * 48;
    const int fr = lane & 15, fg = lane >> 4;

    u16* sA[2] = {(u16*)smem, (u16*)(smem + 57344)};
    u16* sB[2] = {(u16*)(smem + 32768), (u16*)(smem + 90112)};

    const int cs = (((tid & 7) ^ ((tid >> 3) & 7)) << 3);
    const int s8 = (tid & 7) << 3;
    const int rr6 = tid >> 3;

    auto stA = [&](int buf, int k0, int mh) {
#pragma unroll
        for (int j = 0; j < 2; ++j) {
            int r = j * 128 + mh * 64 + rr6;
            gload_lds16(A + (size_t)(bm + r) * K + k0 + cs, sA[buf] + r * 64 + s8);
        }
    };
    auto stB = [&](int buf, int k0, int bt) {
        int r = bt * 64 + rr6;
        gload_lds16(B + (size_t)(bn + r) * K + k0 + cs, sB[buf] + r * 64 + s8);
    };

    f32x4 acc[8][3] = {};
    u16x8 av[4][2], av2[4][2], bv[2][2], bv1[2];
    const int nt = K >> 6;

    stA(0, 0, 0); stA(0, 0, 1); stB(0, 0, 0); stB(0, 0, 1); stB(0, 0, 2);
    stA(1, 64, 0); stA(1, 64, 1);
    VM4
    __builtin_amdgcn_s_barrier();
    __builtin_amdgcn_sched_barrier(0);

    for (int it = 0; it < (nt >> 1); ++it) {
        const int kc = it << 7;
        const int kn1 = kc + 64, kn2 = kc + 128, kn3 = kc + 192;
        const bool st2 = (kn2 < K), st3 = (kn3 < K);

        LDA6(av, 0, 0) LDB0_192(0)
        stB(1, kn1, 0); stB(1, kn1, 1);
        MN0(av, 0) ENDP
        LDB1_192(0) LDA6(av2, 0, 1)
        stB(1, kn1, 2);
        if (st2) stA(0, kn2, 0);
        MN1B ENDP
        if (st2) stA(0, kn2, 1);
        MN0(av2, 1)
        if (st2) { VM4 } else { VM0 }
        ENDP
        LDA6(av, 1, 0) LDB0_192(1)
        if (st2) { stB(0, kn2, 0); stB(0, kn2, 1); }
        MN0(av, 0) ENDP
        LDB1_192(1) LDA6(av2, 1, 1)
        if (st2) stB(0, kn2, 2);
        if (st3) stA(1, kn3, 0);
        MN1B ENDP
        if (st3) stA(1, kn3, 1);
        MN0(av2, 1)
        if (st3) { VM4 } else { VM0 }
        ENDP
    }

#pragma unroll
    for (int am = 0; am < 8; ++am)
#pragma unroll
        for (int bq = 0; bq < 3; ++bq)
#pragma unroll
            for (int r = 0; r < 4; ++r) {
                int row = bm + wr + am * 16 + fg * 4 + r;
                int col = bn + wc + bq * 16 + fr;
                C[(size_t)row * N + col] = f2bf(acc[am][bq][r]);
            }
}

// ---- 128x128 8-phase variant for out-proj (resid epilogue) ----
#define LDAH(BUF, MH)                                                         \
  _Pragma("unroll") for (int mq = 0; mq < 2; ++mq) {                          \
    int ra = wr + (MH) * 32 + mq * 16 + fr;                                   \
    int sw = ra & 7;                                                          \
    _Pragma("unroll") for (int k2 = 0; k2 < 2; ++k2)                          \
      avh[mq][k2] = *(const u16x8*)(sA[BUF] + ra * 64 +                       \
                                    ((((k2 << 2) | fg) ^ sw) << 3));          \
  }

#define LDBH(BUF, NH)                                                         \
  _Pragma("unroll") for (int nq = 0; nq < 2; ++nq) {                          \
    int rb = wc + (NH) * 32 + nq * 16 + fr;                                   \
    int sw = rb & 7;                                                          \
    _Pragma("unroll") for (int k2 = 0; k2 < 2; ++k2)                          \
      bvh[nq][k2] = *(const u16x8*)(sB[BUF] + rb * 64 +                       \
                                    ((((k2 << 2) | fg) ^ sw) << 3));          \
  }

#define MFMAQH(MH, NH)                                                        \
  __builtin_amdgcn_s_barrier();                                               \
  __builtin_amdgcn_s_setprio(1);                                              \
  _Pragma("unroll") for (int k2 = 0; k2 < 2; ++k2)                            \
    _Pragma("unroll") for (int mq = 0; mq < 2; ++mq)                          \
      _Pragma("unroll") for (int nq = 0; nq < 2; ++nq)                        \
        acc[(MH) * 2 + mq][(NH) * 2 + nq] =                                   \
            __builtin_amdgcn_mfma_f32_16x16x32_bf16(                          \
                as_bf(avh[mq][k2]), as_bf(bvh[nq][k2]),                       \
                acc[(MH) * 2 + mq][(NH) * 2 + nq], 0, 0, 0);                  \
  __builtin_amdgcn_s_setprio(0);

__global__ __launch_bounds__(256) void gemm128(const u16* __restrict__ A,
                                               const u16* __restrict__ B,
                                               float* __restrict__ C,
                                               const float* __restrict__ resid,
                                               int M, int N, int K) {
    extern __shared__ char smem[];
    const int tid = threadIdx.x, lane = tid & 63, wid = tid >> 6;
    const int bm = blockIdx.y * 128, bn = blockIdx.x * 128;
    const int wr = (wid >> 1) * 64, wc = (wid & 1) * 64;
    const int fr = lane & 15, fg = lane >> 4;

    u16* sA[2] = {(u16*)smem, (u16*)(smem + 32768)};
    u16* sB[2] = {(u16*)(smem + 16384), (u16*)(smem + 49152)};

    const int cs = (((tid & 7) ^ ((tid >> 3) & 7)) << 3);
    const int s8 = (tid & 7) << 3;
    const int rr5 = tid >> 3;

    auto stA = [&](int buf, int k0, int mh) {
#pragma unroll
        for (int j = 0; j < 2; ++j) {
            int r = j * 64 + mh * 32 + rr5;
            gload_lds16(A + (size_t)(bm + r) * K + k0 + cs, sA[buf] + r * 64 + s8);
        }
    };
    auto stB = [&](int buf, int k0, int nh) {
#pragma unroll
        for (int j = 0; j < 2; ++j) {
            int r = j * 64 + nh * 32 + rr5;
            gload_lds16(B + (size_t)(bn + r) * K + k0 + cs, sB[buf] + r * 64 + s8);
        }
    };

    f32x4 acc[4][4] = {};
    u16x8 avh[2][2], bvh[2][2];
    const int nt = K >> 6;

    stA(0, 0, 0); stA(0, 0, 1); stB(0, 0, 0); stB(0, 0, 1);
    stA(1, 64, 0); stB(1, 64, 1);
    VM4
    __builtin_amdgcn_s_barrier();
    __builtin_amdgcn_sched_barrier(0);

    for (int it = 0; it < (nt >> 1); ++it) {
        const int kc = it << 7;
        const int kn1 = kc + 64, kn2 = kc + 128, kn3 = kc + 192;
        const bool st2 = (kn2 < K), st3 = (kn3 < K);

        LDAH(0, 0) LDBH(0, 0)
        stA(1, kn1, 1);
        MFMAQH(0, 0) ENDP
        LDBH(0, 1)
        stB(1, kn1, 0);
        MFMAQH(0, 1) ENDP
        LDAH(0, 1)
        if (st2) stA(0, kn2, 0);
        MFMAQH(1, 1) ENDP
        LDBH(0, 0)
        if (st2) stB(0, kn2, 1);
        MFMAQH(1, 0)
        if (st2) { VM4 } else { VM0 }
        ENDP
        LDAH(1, 0) LDBH(1, 0)
        if (st2) stA(0, kn2, 1);
        MFMAQH(0, 0) ENDP
        LDBH(1, 1)
        if (st2) stB(0, kn2, 0);
        MFMAQH(0, 1) ENDP
        LDAH(1, 1)
        if (st3) stA(1, kn3, 0);
        MFMAQH(1, 1) ENDP
        LDBH(1, 0)
        if (st3) stB(1, kn3, 1);
        MFMAQH(1, 0)
        VM4
        ENDP
    }

#pragma unroll
    for (int am = 0; am < 4; ++am)
#pragma unroll
        for (int bq = 0; bq < 4; ++bq)
#pragma unroll
            for (int r = 0; r < 4; ++r) {
                int row = bm + wr + am * 16 + fg * 4 + r;
                int col = bn + wc + bq * 16 + fr;
                float val = acc[am][bq][r] + resid[(size_t)row * N + col];
                C[(size_t)row * N + col] = val;
            }
}

// ---------------- per-head RMSNorm + RoPE (vectorized, bf16 qkv) -----------
__global__ __launch_bounds__(256) void rope_split(const u16* __restrict__ qkv,
                                                  const float* __restrict__ cosb,
                                                  const float* __restrict__ sinb,
                                                  u16* __restrict__ q_bf,
                                                  u16* __restrict__ k_bf,
                                                  float* __restrict__ k_out,
                                                  float* __restrict__ v_out) {
    const int t = blockIdx.x, tid = threadIdx.x, wid = tid >> 6, lane = tid & 63;
    const u16* row = qkv + (size_t)t * (3 * DMODEL);
    const int dp = (lane & 31) << 1;
    float2 c2 = *(const float2*)(cosb + t * 64 + dp);
    float2 s2 = *(const float2*)(sinb + t * 64 + dp);
    const bool hi = lane >= 32;

    for (int task = wid; task < 32; task += 4) {
        u32 w = *(const u32*)(row + task * 128 + lane * 2);
        float xa = lo2f(w), xb = hi2f(w);
        float ss = xa * xa + xb * xb;
#pragma unroll
        for (int off = 32; off; off >>= 1) ss += __shfl_xor(ss, off);
        float rn = rsqrtf(ss * (1.f / 128.f) + 1e-6f);
        float pa = __shfl_xor(xa, 32), pb = __shfl_xor(xb, 32);
        float oa, ob;
        if (!hi) {
            oa = (xa * c2.x - pa * s2.x) * rn;
            ob = (xb * c2.y - pb * s2.y) * rn;
        } else {
            oa = (pa * s2.x + xa * c2.x) * rn;
            ob = (pb * s2.y + xb * c2.y) * rn;
        }
        u32 pk = (u32)f2bf(oa) | ((u32)f2bf(ob) << 16);
        if (task < 16) {
            *(u32*)(q_bf + ((size_t)task * T_SEQ + t) * 128 + lane * 2) = pk;
        } else {
            int hh = task - 16;
            *(u32*)(k_bf + ((size_t)hh * T_SEQ + t) * 128 + lane * 2) = pk;
            float2 kk; kk.x = oa; kk.y = ob;
            *(float2*)(k_out + (size_t)t * DMODEL + hh * 128 + lane * 2) = kk;
        }
    }
    {
        u16x8 vv = *(const u16x8*)(row + 2 * DMODEL + tid * 8);
        float4 f0, f1;
        f0.x = bf2f(vv[0]); f0.y = bf2f(vv[1]); f0.z = bf2f(vv[2]); f0.w = bf2f(vv[3]);
        f1.x = bf2f(vv[4]); f1.y = bf2f(vv[5]); f1.z = bf2f(vv[6]); f1.w = bf2f(vv[7]);
        *(float4*)(v_out + (size_t)t * DMODEL + tid * 8) = f0;
        *(float4*)(v_out + (size_t)t * DMODEL + tid * 8 + 4) = f1;
    }
}

// ---------------- V transpose: qkv bf16 -> vt bf16 [h][128][T] -------------
__global__ __launch_bounds__(256) void vtrans(const u16* __restrict__ qkv,
                                              u16* __restrict__ vt) {
    const int b = blockIdx.x, tid = threadIdx.x;
    const int head = b >> 7;
    const int i = (b & 127) * 256 + tid;
    const int d = i & 127, tc = i >> 7;
    u16x8 o;
#pragma unroll
    for (int j = 0; j < 8; ++j)
        o[j] = qkv[(size_t)(tc * 8 + j) * (3 * DMODEL) + 2 * DMODEL + head * 128 + d];
    *(u16x8*)&vt[((size_t)head * 128 + d) * T_SEQ + tc * 8] = o;
}

// ---------------- causal flash attention, kv-split (r15 best) --------------
// Two-stage wait: K gloads issued first, vmcnt(4) -> QK^T while V (4 youngest)
// still in flight; vmcnt(0) before PV. No extra registers; 3 barriers/tile.
__global__ __launch_bounds__(256) void attn_part(const u16* __restrict__ qb,
                                                 const u16* __restrict__ kb,
                                                 const u16* __restrict__ vtb,
                                                 u16* __restrict__ opart,
                                                 float* __restrict__ ml) {
    __shared__ u16 Ks[64 * 128];
    __shared__ u16 Vs[128 * 64];
    __shared__ u16 Ps[4][16 * 64];

    const int bid = blockIdx.x;
    const int r8 = bid & 7, s = bid >> 3;
    const int hs = s >> 6, g = (s >> 5) & 1, m = s & 31;
    const int head = r8 + (hs << 3);
    const int qt = g ? (31 - m) : m;
    const int nt = qt + 1;
    const int h0c = (nt + 1) >> 1;
    const int first = g ? h0c : 0;
    const int count = g ? (nt - h0c) : h0c;
    const int pidx = (head * 32 + qt) * 2 + g;

    const int tid = threadIdx.x, wid = tid >> 6, lane = tid & 63;
    const int fr = lane & 15, fg = lane >> 4;
    const u16* kh = kb + (size_t)head * T_SEQ * 128;
    const u16* vth = vtb + (size_t)head * 128 * T_SEQ;
    const u16* qh = qb + (size_t)head * T_SEQ * 128;
    const int q0 = qt * 64 + wid * 16;
    const int qrow_g = q0 + fr;

    u16x8 bq[4];
    {
        const u16* qrow = qh + (size_t)(q0 + fr) * 128 + fg * 8;
#pragma unroll
        for (int cc = 0; cc < 4; ++cc) bq[cc] = *(const u16x8*)(qrow + cc * 32);
    }

    auto stage = [&](int kv0) {
        // K first (oldest 4 vmem ops), then V; order pinned by sched_barrier
#pragma unroll
        for (int i = 0; i < 4; ++i) {
            int idx = i * 256 + tid;
            int r = idx >> 4;
            int cbs = ((idx & 15) << 4) ^ ((r & 7) << 4);
            gload_lds16(kh + (size_t)(kv0 + r) * 128 + (cbs >> 1), &Ks[idx * 8]);
        }
        __builtin_amdgcn_sched_barrier(0);
#pragma unroll
        for (int i = 0; i < 4; ++i) {
            int idx = i * 256 + tid;
            int d = idx >> 3;
            int cbs = ((idx & 7) << 4) ^ ((d & 7) << 4);
            gload_lds16(vth + (size_t)d * T_SEQ + kv0 + (cbs >> 1), &Vs[idx * 8]);
        }
    };

    f32x4 o[8] = {};
    float m_run = -1e30f, l_run = 0.f;

    for (int i = 0; i < count; ++i) {
        const int kv0 = (first + i) * 64;
        stage(kv0);
        asm volatile("s_waitcnt vmcnt(4)" ::: "memory");   // K landed
        __builtin_amdgcn_s_barrier();
        __builtin_amdgcn_sched_barrier(0);

        const char* ksb = (const char*)&Ks[0];
        const char* vsb = (const char*)&Vs[0];
        char* psb = (char*)&Ps[wid][0];

        float p[4][4];
        float mx = -1e30f;
        const bool diag = (kv0 + 64 > q0);
#pragma unroll
        for (int st = 0; st < 4; ++st) {
            f32x4 sacc = {0.f, 0.f, 0.f, 0.f};
#pragma unroll
            for (int c4 = 0; c4 < 4; ++c4) {
                int r = st * 16 + fr;
                int cb = c4 * 64 + fg * 16;
                u16x8 ak = *(const u16x8*)(ksb + r * 256 + (cb ^ ((r & 7) << 4)));
                sacc = __builtin_amdgcn_mfma_f32_16x16x32_bf16(
                    as_bf(ak), as_bf(bq[c4]), sacc, 0, 0, 0);
            }
#pragma unroll
            for (int rr = 0; rr < 4; ++rr) {
                float sv = sacc[rr] * ATT_SCALE;
                if (diag) {
                    int kvg = kv0 + st * 16 + fg * 4 + rr;
                    sv = (kvg <= qrow_g) ? sv : -1e30f;
                }
                p[st][rr] = sv;
                mx = fmaxf(mx, sv);
            }
        }
        mx = fmaxf(mx, __shfl_xor(mx, 16));
        mx = fmaxf(mx, __shfl_xor(mx, 32));

        if (__all(mx - m_run <= 8.f)) {
            float rs = 0.f;
#pragma unroll
            for (int st = 0; st < 4; ++st) {
                u16x4 pw;
#pragma unroll
                for (int rr = 0; rr < 4; ++rr) {
                    float e = __expf(p[st][rr] - m_run);
                    rs += e;
                    pw[rr] = f2bf(e);
                }
                *(u16x4*)(psb + fr * 128 + ((st * 32 + fg * 8) ^ ((fr & 7) << 4))) = pw;
            }
            rs += __shfl_xor(rs, 16);
            rs += __shfl_xor(rs, 32);
            l_run += rs;
        } else {
            float m_new = fmaxf(m_run, mx);
            float corr = __expf(m_run - m_new);
            float rs = 0.f;
#pragma unroll
            for (int st = 0; st < 4; ++st) {
                u16x4 pw;
#pragma unroll
                for (int rr = 0; rr < 4; ++rr) {
                    float e = __expf(p[st][rr] - m_new);
                    rs += e;
                    pw[rr] = f2bf(e);
                }
                *(u16x4*)(psb + fr * 128 + ((st * 32 + fg * 8) ^ ((fr & 7) << 4))) = pw;
            }
            rs += __shfl_xor(rs, 16);
            rs += __shfl_xor(rs, 32);
            l_run = l_run * corr + rs;
            m_run = m_new;
            float ct[4];
#pragma unroll
            for (int rr = 0; rr < 4; ++rr) ct[rr] = __shfl(corr, fg * 4 + rr);
#pragma unroll
            for (int f = 0; f < 8; ++f)
#pragma unroll
                for (int rr = 0; rr < 4; ++rr) o[f][rr] *= ct[rr];
        }

        asm volatile("s_waitcnt vmcnt(0)" ::: "memory");   // V landed
        __builtin_amdgcn_s_barrier();
        __builtin_amdgcn_sched_barrier(0);

#pragma unroll
        for (int ks = 0; ks < 2; ++ks) {
            u16x8 pa = *(const u16x8*)(psb + fr * 128 + ((ks * 64 + fg * 16) ^ ((fr & 7) << 4)));
#pragma unroll
            for (int f = 0; f < 8; ++f) {
                int d = f * 16 + fr;
                u16x8 vB = *(const u16x8*)(vsb + d * 128 + ((ks * 64 + fg * 16) ^ ((d & 7) << 4)));
                o[f] = __builtin_amdgcn_mfma_f32_16x16x32_bf16(
                    as_bf(pa), as_bf(vB), o[f], 0, 0, 0);
            }
        }
        __builtin_amdgcn_s_barrier();       // all waves done reading before next stage
        __builtin_amdgcn_sched_barrier(0);
    }

    u16* op = opart + (size_t)pidx * 8192;
#pragma unroll
    for (int f = 0; f < 8; ++f)
#pragma unroll
        for (int rr = 0; rr < 4; ++rr)
            op[(wid * 16 + fg * 4 + rr) * 128 + f * 16 + fr] = f2bf(o[f][rr]);
    if (fg == 0) {
        ml[pidx * 128 + wid * 16 + fr] = m_run;
        ml[pidx * 128 + 64 + wid * 16 + fr] = l_run;
    }
}

// ---------------- merge kv-split partials -> x_bf --------------------------
__global__ __launch_bounds__(256) void attn_merge(const u16* __restrict__ opart,
                                                  const float* __restrict__ ml,
                                                  u16* __restrict__ xout) {
    const int b = blockIdx.x, tid = threadIdx.x;
    const int head = b >> 5, qt = b & 31;
    const int p0 = b * 2, p1 = b * 2 + 1;
    const int row = tid >> 2, d0 = (tid & 3) * 32;

    float m0 = ml[p0 * 128 + row], l0 = ml[p0 * 128 + 64 + row];
    float m1 = ml[p1 * 128 + row], l1 = ml[p1 * 128 + 64 + row];
    float M = fmaxf(m0, m1);
    float w0 = __expf(m0 - M), w1 = __expf(m1 - M);
    float inv = 1.f / (l0 * w0 + l1 * w1);
    w0 *= inv; w1 *= inv;

    const u16* a0 = opart + (size_t)p0 * 8192 + row * 128 + d0;
    const u16* a1 = opart + (size_t)p1 * 8192 + row * 128 + d0;
    u16* dst = xout + (size_t)(qt * 64 + row) * DMODEL + head * 128 + d0;
#pragma unroll
    for (int j = 0; j < 4; ++j) {
        u16x8 v0 = *(const u16x8*)(a0 + j * 8);
        u16x8 v1 = *(const u16x8*)(a1 + j * 8);
        u16x8 ov;
#pragma unroll
        for (int e = 0; e < 8; ++e)
            ov[e] = f2bf(bf2f(v0[e]) * w0 + bf2f(v1[e]) * w1);
        *(u16x8*)(dst + j * 8) = ov;
    }
}

extern "C" void kernel_launch(void* const* d_in, const int* in_sizes, int n_in,
                              void* d_out, int out_size, void* d_ws, size_t ws_size,
                              hipStream_t stream) {
    const float* x_in = (const float*)d_in[0];
    const float* w_qkv = (const float*)d_in[1];
    const float* w_o = (const float*)d_in[2];
    const float* cosb = (const float*)d_in[3];
    const float* sinb = (const float*)d_in[4];

    float* out = (float*)d_out;
    float* k_out = out + 4194304;
    float* v_out = out + 8388608;

    char* ws = (char*)d_ws;
    u16* xn    = (u16*)(ws);                         // 8 MiB  [T][D] bf16
    u16* w_bf  = (u16*)(ws + (size_t)(8u << 20));    // 24 MiB [3D][D] bf16
    u16* o_bf  = (u16*)(ws + (size_t)(32u << 20));   // 8 MiB  [D][D] bf16
    u16* qkv   = (u16*)(ws + (size_t)(40u << 20));   // 24 MiB [T][3D] bf16
    u16* q_bf  = (u16*)(ws + (size_t)(64u << 20));   // 8 MiB  [h][T][hd]
    u16* k_bf  = (u16*)(ws + (size_t)(72u << 20));   // 8 MiB
    u16* vt_bf = (u16*)(ws + (size_t)(80u << 20));   // 8 MiB  [h][hd][T]
    u16* x_bf  = (u16*)(ws + (size_t)(88u << 20));   // 8 MiB  [T][D]
    u16* opart = (u16*)(ws + (size_t)(40u << 20));   // 16 MiB (aliases dead qkv)
    float* mlb = (float*)(ws + (size_t)(56u << 20)); // 512 KiB

    (void)hipFuncSetAttribute(reinterpret_cast<const void*>(&gemm192),
                              hipFuncAttributeMaxDynamicSharedMemorySize, 114688);
    (void)hipFuncSetAttribute(reinterpret_cast<const void*>(&gemm128),
                              hipFuncAttributeMaxDynamicSharedMemorySize, 65536);

    prep<<<10240, 256, 0, stream>>>(w_qkv, w_o, x_in, w_bf, o_bf, xn);
    gemm192<<<dim3(32, 8), 512, 114688, stream>>>(xn, w_bf, qkv, 2048, 6144, 2048);
    rope_split<<<2048, 256, 0, stream>>>(qkv, cosb, sinb, q_bf, k_bf, k_out, v_out);
    vtrans<<<2048, 256, 0, stream>>>(qkv, vt_bf);
    attn_part<<<1024, 256, 0, stream>>>(q_bf, k_bf, vt_bf, opart, mlb);
    attn_merge<<<512, 256, 0, stream>>>(opart, mlb, x_bf);
    gemm128<<<dim3(16, 16), 256, 65536, stream>>>(x_bf, o_bf, out, x_in, 2048, 2048, 2048);
}